// Round 6
// baseline (241.384 us; speedup 1.0000x reference)
//
#include <hip/hip_runtime.h>
#include <hip/hip_bf16.h>

typedef __bf16 bf16;
typedef __attribute__((ext_vector_type(4))) __bf16 bf16x4;
typedef __attribute__((ext_vector_type(8))) __bf16 bf16x8;
typedef __attribute__((ext_vector_type(4))) float floatx4;

#define NSLOT 16   // rowsum partial slots per row: 8 n-blocks x 2 wave-cols (scores geometry)

// async global->LDS, 16B per lane. LDS dest is wave-uniform base + lane*16 (HW-fixed);
// the GLOBAL source chunk is swizzled so LDS frag reads are conflict-free (R5/R9: conflicts 0).
__device__ __forceinline__ void gl_lds16(const bf16* g, bf16* l) {
    __builtin_amdgcn_global_load_lds(
        (const __attribute__((address_space(1))) unsigned int*)g,
        (__attribute__((address_space(3))) unsigned int*)l,
        16, 0, 0);
}

// 4(m) x 2(n) supertile swizzle: consecutive dispatch ids share A/B bands (L2 locality).
// Requires gridDim.x % 4 == 0 and gridDim.y % 2 == 0. Bijective on the grid.
__device__ __forceinline__ void swizzle_mn(int& bm, int& bn) {
    int gx = gridDim.x;
    int f  = blockIdx.y * gx + blockIdx.x;
    int st = f >> 3, r = f & 7;
    int mgroups = gx >> 2;
    bm = (st % mgroups) * 4 + (r & 3);
    bn = (st / mgroups) * 2 + (r >> 2);
}

// ---------------------------------------------------------------- x fp32 [R,C] -> xb bf16 [R,C] AND xt bf16 [C,R]
__global__ __launch_bounds__(256) void cast_both(const float* __restrict__ in,
                                                 bf16* __restrict__ outn,
                                                 bf16* __restrict__ outt,
                                                 int R, int C) {
    __shared__ float tile[64][65];
    const long long bz = blockIdx.z;
    in   += bz * (long long)R * C;
    outn += bz * (long long)R * C;
    outt += bz * (long long)R * C;
    const int r0 = blockIdx.x * 64, c0 = blockIdx.y * 64;
    const int cl = (threadIdx.x & 15) * 4;   // col offset within tile
    const int rw = threadIdx.x >> 4;         // 0..15
#pragma unroll
    for (int it = 0; it < 4; ++it) {
        const int r = rw + it * 16;
        floatx4 v = *(const floatx4*)&in[(long long)(r0 + r) * C + c0 + cl];
        bf16x4 b; b[0] = (bf16)v[0]; b[1] = (bf16)v[1]; b[2] = (bf16)v[2]; b[3] = (bf16)v[3];
        *(bf16x4*)&outn[(long long)(r0 + r) * C + c0 + cl] = b;
        tile[r][cl + 0] = v[0]; tile[r][cl + 1] = v[1];
        tile[r][cl + 2] = v[2]; tile[r][cl + 3] = v[3];
    }
    __syncthreads();
#pragma unroll
    for (int it = 0; it < 4; ++it) {
        const int c = rw + it * 16;          // original col = outt row
        bf16x4 b;
        b[0] = (bf16)tile[cl + 0][c]; b[1] = (bf16)tile[cl + 1][c];
        b[2] = (bf16)tile[cl + 2][c]; b[3] = (bf16)tile[cl + 3][c];
        *(bf16x4*)&outt[(long long)(c0 + c) * R + r0 + cl] = b;
    }
}

// ---------------------------------------------------------------- fp32 [R,C] -> bf16 [C,R] (for W, 512x512: ~2us)
__global__ __launch_bounds__(256) void cast_transpose(const float* __restrict__ in,
                                                      bf16* __restrict__ out,
                                                      int R, int C) {
    __shared__ float tile[32][33];
    const int r0 = blockIdx.x * 32, c0 = blockIdx.y * 32;
    const int tx = threadIdx.x & 31, ty = threadIdx.x >> 5;
#pragma unroll
    for (int i = 0; i < 32; i += 8)
        tile[ty + i][tx] = in[(long long)(r0 + ty + i) * C + (c0 + tx)];
    __syncthreads();
#pragma unroll
    for (int i = 0; i < 32; i += 8)
        out[(long long)(c0 + ty + i) * R + (r0 + tx)] = (bf16)tile[tx][ty + i];
}

// tanh via one exp + one rcp; exact saturation at +-1. (R7: poly outer-exp regressed; keep __expf.)
__device__ __forceinline__ float fast_tanh(float v) {
    float e = __expf(2.0f * v);
    return 1.0f - 2.0f / (e + 1.0f);
}

// ---------------------------------------------------------------- fat-wave-tile NT GEMM, BK=64
// R14: LDS-BW diagnosis — 5 schedule/occupancy variants all pinned at ~480 TF / 19% MfmaUtil
// because per-kFLOP LDS traffic ((Mw+Nw)/(Mw*Nw)) was invariant: 64x64 tiles demand ~180 B/cy
// aggregate vs 128 B/cy LDS peak (85 achieved for b128). Fix = bigger wave tiles:
//   MODE 1 (scores): block 256x256, 4 waves 2x2, wave 128x128 -> 15.6 B/kFLOP (-50%), acc 256 VGPR.
//   MODE 0/2:        block 128x256, 4 waves 1x4, wave 128x64  -> 23.4 B/kFLOP (-25%), acc 128 VGPR.
// Same proven 2-phase dbuf loop, staging swizzle, frag swizzle as R9 (conflicts 0).
// MODE 0 (proj): store bf16 C.   MODE 1: exp(tanh(v)) + rowsum partials.   MODE 2 (PV): v*invRowsum.
template <int MODE>
__global__ __launch_bounds__(256) void gemm_fat(const bf16* __restrict__ A,
                                                const bf16* __restrict__ Bm,
                                                void* __restrict__ Cout,
                                                float* __restrict__ rpart,
                                                int M, int N, int K,
                                                long long batchA, long long batchB,
                                                long long batchC, long long batchR) {
    constexpr int BM  = (MODE == 1) ? 256 : 128;   // block rows
    constexpr int WN  = (MODE == 1) ? 128 : 64;    // wave cols
    constexpr int NWN = 256 / WN;                  // waves along N (2 or 4)
    constexpr int NJ  = WN / 16;                   // B-frags per wave (8 or 4)

    const long long bz = blockIdx.z;
    A  += bz * batchA;
    Bm += bz * batchB;

    __shared__ bf16 As[2][BM * 64];    // MODE1: 64 KB, else 32 KB
    __shared__ bf16 Bs[2][256 * 64];   // 64 KB
    __shared__ float rs[128];          // MODE 2 only

    const int t    = threadIdx.x;
    const int lane = t & 63;
    const int w    = t >> 6;
    const int quad = lane >> 4;
    const int l16  = lane & 15;
    const int wr   = w / NWN;          // 0..1 (MODE1) or 0
    const int wc   = w % NWN;          // 0..1 (MODE1) or 0..3

    int bm, bn;
    swizzle_mn(bm, bn);
    const int m0 = bm * BM;
    const int n0 = bn * 256;

    floatx4 acc[8][NJ] = {};

    // staging: thread t -> row ra (+32 per instr), global chunk (t&7)^(ra&7) (R9-proven swizzle).
    const int ra = t >> 3;
    const int ca = ((t & 7) ^ (ra & 7)) * 8;
    const long long rstep = 32LL * K;
    const bf16* Abase = A + (long long)(m0 + ra) * K + ca;
    const bf16* Bbase = Bm + (long long)(n0 + ra) * K + ca;

    // MODE 2: fold softmax denominators into rs[] up front (read after K-loop's final barrier).
    if (MODE == 2) {
        if (t < 128) {
            const float* pp = rpart + (bz * batchR + m0 + t) * NSLOT;
            float s = 0.f;
#pragma unroll
            for (int c = 0; c < NSLOT / 4; ++c) {
                float4 p = ((const float4*)pp)[c];
                s += (p.x + p.y) + (p.z + p.w);
            }
            rs[t] = 1.0f / s;
        }
    }

    auto stage = [&](int buf, int k0) {   // BM/32 + 8 gl_lds16 per thread
#pragma unroll
        for (int i = 0; i < BM / 32; ++i)
            gl_lds16(Abase + k0 + i * rstep, &As[buf][(t + 256 * i) * 8]);
#pragma unroll
        for (int i = 0; i < 8; ++i)
            gl_lds16(Bbase + k0 + i * rstep, &Bs[buf][(t + 256 * i) * 8]);
    };

    auto compute = [&](int buf) {
#pragma unroll
        for (int s = 0; s < 2; ++s) {
            const int cq = ((s * 4 + quad) ^ (l16 & 7)) * 8;
            bf16x8 af[8], bfr[NJ];
#pragma unroll
            for (int i = 0; i < 8; ++i)
                af[i] = *(const bf16x8*)(&As[buf][(wr * 128 + i * 16 + l16) * 64 + cq]);
#pragma unroll
            for (int j = 0; j < NJ; ++j)
                bfr[j] = *(const bf16x8*)(&Bs[buf][(wc * WN + j * 16 + l16) * 64 + cq]);
#pragma unroll
            for (int i = 0; i < 8; ++i)
#pragma unroll
                for (int j = 0; j < NJ; ++j)
                    acc[i][j] = __builtin_amdgcn_mfma_f32_16x16x32_bf16(af[i], bfr[j], acc[i][j], 0, 0, 0);
        }
    };

    stage(0, 0);
    __syncthreads();
    for (int k0 = 0; k0 < K; k0 += 128) {
        if (k0 + 64 < K) stage(1, k0 + 64);      // prefetch in flight during compute(0)
        compute(0);
        __syncthreads();
        if (k0 + 128 < K) stage(0, k0 + 128);
        compute(1);
        __syncthreads();
    }

    if (MODE == 1) {
        bf16* Cg = (bf16*)Cout + bz * batchC;
        const int slot = bn * NWN + wc;          // 8 n-blocks x 2 wave-cols = 16 slots
#pragma unroll
        for (int i = 0; i < 8; ++i)
#pragma unroll
            for (int r = 0; r < 4; ++r) {
                long long row = m0 + wr * 128 + i * 16 + quad * 4 + r;
                float s = 0.f;
#pragma unroll
                for (int j = 0; j < NJ; ++j) {
                    float v = __expf(fast_tanh(acc[i][j][r]));
                    s += v;
                    Cg[row * (long long)N + (n0 + wc * WN + j * 16 + l16)] = (bf16)v;
                }
#pragma unroll
                for (int msk = 1; msk < 16; msk <<= 1) s += __shfl_xor(s, msk);
                if (l16 == 0)
                    rpart[(bz * batchR + row) * NSLOT + slot] = s;   // plain store, race-free
            }
    } else if (MODE == 2) {
        float* Og = (float*)Cout + bz * batchC;
#pragma unroll
        for (int i = 0; i < 8; ++i)
#pragma unroll
            for (int r = 0; r < 4; ++r) {
                int rl = i * 16 + quad * 4 + r;  // wr == 0 for MODE 2
                float inv = rs[rl];
                long long row = m0 + rl;
#pragma unroll
                for (int j = 0; j < NJ; ++j)
                    Og[row * (long long)N + (n0 + wc * WN + j * 16 + l16)] = acc[i][j][r] * inv;
            }
    } else {
        bf16* Cg = (bf16*)Cout + bz * batchC;
#pragma unroll
        for (int i = 0; i < 8; ++i)
#pragma unroll
            for (int r = 0; r < 4; ++r) {
                long long row = m0 + i * 16 + quad * 4 + r;   // wr == 0 for MODE 0
#pragma unroll
                for (int j = 0; j < NJ; ++j)
                    Cg[row * (long long)N + (n0 + wc * WN + j * 16 + l16)] = (bf16)acc[i][j][r];
            }
    }
}

// ----------------------------------------------------------------
extern "C" void kernel_launch(void* const* d_in, const int* in_sizes, int n_in,
                              void* d_out, int out_size, void* d_ws, size_t ws_size,
                              hipStream_t stream) {
    const int B = 8, S = 2048, D = 512;
    const float* x = (const float*)d_in[0];
    const float* W = (const float*)d_in[1];
    float* out = (float*)d_out;

    const size_t nx = (size_t)B * S * D;
    const size_t nw = (size_t)D * D;

    char* ws = (char*)d_ws;
    auto al = [](size_t v) { return (v + 255) & ~(size_t)255; };
    size_t off = 0;
    bf16* xb = (bf16*)(ws + off); off = al(off + nx * 2);          // x bf16 [B,S,D]
    bf16* xt = (bf16*)(ws + off); off = al(off + nx * 2);          // x^T bf16 [B,D,S]
    bf16* pb = (bf16*)(ws + off); off = al(off + nx * 2);          // proj bf16 [B,S,D]
    bf16* wt = (bf16*)(ws + off); off = al(off + nw * 2);          // W^T bf16 [D,D]
    float* rpart = (float*)(ws + off); off = al(off + (size_t)B * S * NSLOT * 4);  // rowsum partials
    bf16* sb = (bf16*)(ws + off);                                  // P_unnorm bf16
    const size_t full_need = off + (size_t)B * S * S * 2;
    const bool batched = (ws_size >= full_need);

    { dim3 g(S / 64, D / 64, B); cast_both<<<g, 256, 0, stream>>>(x, xb, xt, S, D); }
    { dim3 g(D / 32, D / 32, 1); cast_transpose<<<g, 256, 0, stream>>>(W, wt, D, D); }

    // proj: pb[BS,D] = xb @ wt^T   (128x256 tiles, grid 128x2 = 256 blocks = 1/CU)
    {
        dim3 g(B * S / 128, D / 256, 1);
        gemm_fat<0><<<g, 256, 0, stream>>>(xb, wt, (void*)pb, nullptr, B * S, D, D, 0, 0, 0, 0);
    }

    const long long sd = (long long)S * D;
    const long long ss = (long long)S * S;

    if (batched) {
        // P_un = exp(tanh(pb @ xb^T)), rowsum partials   (256x256 tiles, grid 8x8x8 = 512)
        dim3 g2(S / 256, S / 256, B);
        gemm_fat<1><<<g2, 256, 0, stream>>>(pb, xb, (void*)sb, rpart, S, S, D, sd, sd, ss, S);
        // out = (P_un @ xt^T) * invRowsum                (128x256 tiles, grid 16x2x8 = 256 = 1/CU)
        dim3 g4(S / 128, D / 256, B);
        gemm_fat<2><<<g4, 256, 0, stream>>>(sb, xt, (void*)out, rpart, S, D, S, ss, sd, sd, S);
    } else {
        for (int b = 0; b < B; ++b) {
            dim3 g2(S / 256, S / 256, 1);
            gemm_fat<1><<<g2, 256, 0, stream>>>(pb + (size_t)b * sd, xb + (size_t)b * sd,
                                                (void*)sb, rpart + (size_t)b * S * NSLOT,
                                                S, S, D, 0, 0, 0, S);
            dim3 g4(S / 128, D / 256, 1);
            gemm_fat<2><<<g4, 256, 0, stream>>>(sb, xt + (size_t)b * sd,
                                                (void*)(out + (size_t)b * sd), rpart + (size_t)b * S * NSLOT,
                                                S, D, S, 0, 0, 0, S);
        }
    }
}

// Round 7
// 223.261 us; speedup vs baseline: 1.0812x; 1.0812x over previous
//
#include <hip/hip_runtime.h>
#include <hip/hip_bf16.h>

typedef __bf16 bf16;
typedef __attribute__((ext_vector_type(4))) __bf16 bf16x4;
typedef __attribute__((ext_vector_type(8))) __bf16 bf16x8;
typedef __attribute__((ext_vector_type(4))) float floatx4;

#define NSLOT 32   // rowsum partial slots per row: 16 n-blocks x 2 wave-cols

// async global->LDS, 16B per lane. LDS dest is wave-uniform base + lane*16 (HW-fixed);
// the GLOBAL source chunk is swizzled so LDS frag reads are conflict-free (R5/R12: conflicts 0).
__device__ __forceinline__ void gl_lds16(const bf16* g, bf16* l) {
    __builtin_amdgcn_global_load_lds(
        (const __attribute__((address_space(1))) unsigned int*)g,
        (__attribute__((address_space(3))) unsigned int*)l,
        16, 0, 0);
}

// 4(m) x 2(n) supertile swizzle: consecutive dispatch ids share A/B bands (L2 locality).
// Requires gridDim.x % 4 == 0 and gridDim.y % 2 == 0. Bijective on the grid.
__device__ __forceinline__ void swizzle_mn(int& bm, int& bn) {
    int gx = gridDim.x;
    int f  = blockIdx.y * gx + blockIdx.x;
    int st = f >> 3, r = f & 7;
    int mgroups = gx >> 2;
    bm = (st % mgroups) * 4 + (r & 3);
    bn = (st / mgroups) * 2 + (r >> 2);
}

// ---------------------------------------------------------------- x fp32 [R,C] -> xb bf16 [R,C] AND xt bf16 [C,R]
__global__ __launch_bounds__(256) void cast_both(const float* __restrict__ in,
                                                 bf16* __restrict__ outn,
                                                 bf16* __restrict__ outt,
                                                 int R, int C) {
    __shared__ float tile[64][65];
    const long long bz = blockIdx.z;
    in   += bz * (long long)R * C;
    outn += bz * (long long)R * C;
    outt += bz * (long long)R * C;
    const int r0 = blockIdx.x * 64, c0 = blockIdx.y * 64;
    const int cl = (threadIdx.x & 15) * 4;   // col offset within tile
    const int rw = threadIdx.x >> 4;         // 0..15
#pragma unroll
    for (int it = 0; it < 4; ++it) {
        const int r = rw + it * 16;
        floatx4 v = *(const floatx4*)&in[(long long)(r0 + r) * C + c0 + cl];
        bf16x4 b; b[0] = (bf16)v[0]; b[1] = (bf16)v[1]; b[2] = (bf16)v[2]; b[3] = (bf16)v[3];
        *(bf16x4*)&outn[(long long)(r0 + r) * C + c0 + cl] = b;
        tile[r][cl + 0] = v[0]; tile[r][cl + 1] = v[1];
        tile[r][cl + 2] = v[2]; tile[r][cl + 3] = v[3];
    }
    __syncthreads();
#pragma unroll
    for (int it = 0; it < 4; ++it) {
        const int c = rw + it * 16;          // original col = outt row
        bf16x4 b;
        b[0] = (bf16)tile[cl + 0][c]; b[1] = (bf16)tile[cl + 1][c];
        b[2] = (bf16)tile[cl + 2][c]; b[3] = (bf16)tile[cl + 3][c];
        *(bf16x4*)&outt[(long long)(c0 + c) * R + r0 + cl] = b;
    }
}

// ---------------------------------------------------------------- fp32 [R,C] -> bf16 [C,R] (for W, 512x512: ~2us)
__global__ __launch_bounds__(256) void cast_transpose(const float* __restrict__ in,
                                                      bf16* __restrict__ out,
                                                      int R, int C) {
    __shared__ float tile[32][33];
    const int r0 = blockIdx.x * 32, c0 = blockIdx.y * 32;
    const int tx = threadIdx.x & 31, ty = threadIdx.x >> 5;
#pragma unroll
    for (int i = 0; i < 32; i += 8)
        tile[ty + i][tx] = in[(long long)(r0 + ty + i) * C + (c0 + tx)];
    __syncthreads();
#pragma unroll
    for (int i = 0; i < 32; i += 8)
        out[(long long)(c0 + ty + i) * R + (r0 + tx)] = (bf16)tile[tx][ty + i];
}

// tanh via one exp + one rcp; exact saturation at +-1. (R7: poly outer-exp regressed; keep __expf.)
__device__ __forceinline__ float fast_tanh(float v) {
    float e = __expf(2.0f * v);
    return 1.0f - 2.0f / (e + 1.0f);
}

// ---------------------------------------------------------------- 256(M)x128(N) tile, 512 thr, BK=32
// R15: the residency-cap experiment. Observation: every 256-thread config (R8/R9/R12/R13) sat at
// ~2 workgroups/CU (OccupancyPercent ~20-27%) REGARDLESS of LDS request (32-64 KB) — i.e. the
// harness caps blocks/CU near 2, so 256-thr blocks can never exceed 8 waves/CU (2/SIMD), which is
// the TLP starvation behind the universal ~480 TF wall (m97's 912 TF ran 12 waves/CU, m114).
// Fix under that constraint: 512-thread blocks. 8 waves (4Mx2N), same proven 64x64 wave tiles,
// BK=32 double-buffer -> LDS 48 KB -> 2 blocks/CU even at coarse granularity = 16 waves/CU.
// __launch_bounds__(512,4) caps VGPR at 128 (this wave tile compiled at 72 in R12).
// Staging/read swizzles identical to R12 (verified SQ_LDS_BANK_CONFLICT = 0).
// MODE 0 (proj): bf16 C.  MODE 1 (scores): bf16 exp(tanh(v)) + rowsum partials.  MODE 2 (PV): fp32 v*invRowsum.
template <int MODE>
__global__ __launch_bounds__(512, 4) void gemm512(const bf16* __restrict__ A,
                                                  const bf16* __restrict__ Bm,
                                                  void* __restrict__ Cout,
                                                  float* __restrict__ rpart,
                                                  int M, int N, int K,
                                                  long long batchA, long long batchB,
                                                  long long batchC, long long batchR) {
    const long long bz = blockIdx.z;
    A  += bz * batchA;
    Bm += bz * batchB;

    __shared__ bf16 As[2][256 * 32];   // 2 x 16 KB
    __shared__ bf16 Bs[2][128 * 32];   // 2 x 8 KB
    __shared__ float rs[256];          // MODE 2 only

    const int t    = threadIdx.x;      // 0..511
    const int lane = t & 63;
    const int w    = t >> 6;           // 0..7
    const int quad = lane >> 4;
    const int l16  = lane & 15;
    const int wr   = w >> 1;           // 0..3 : M block of 64
    const int wc   = w & 1;            // 0..1 : N block of 64

    int bm, bn;
    swizzle_mn(bm, bn);
    const int m0 = bm * 256;
    const int n0 = bn * 128;

    floatx4 acc[4][4] = {};

    // staging: thread t covers row srow (A: +128 on 2nd instr), global chunk (t&3)^((t>>3)&3).
    // LDS dest linear in t (= wave-uniform base + lane*16, as gl_lds requires).
    const int srow = t >> 2;                         // 0..127
    const int sch  = (((t & 3) ^ ((t >> 3) & 3))) * 8;
    const bf16* Abase = A + (long long)(m0 + srow) * K + sch;
    const bf16* Bbase = Bm + (long long)(n0 + srow) * K + sch;
    const long long r128 = 128LL * K;

    // frag reads: logical chunk quad after inverse swizzle (2-way max aliasing = free, m136)
    const int rdch = (quad ^ ((l16 >> 1) & 3)) * 8;

    // MODE 2: fold softmax denominators (sum of NSLOT partials per row) into rs[] up front.
    if (MODE == 2) {
        if (t < 256) {
            const float* pp = rpart + (bz * batchR + m0 + t) * NSLOT;
            float s = 0.f;
#pragma unroll
            for (int c = 0; c < NSLOT / 4; ++c) {
                float4 p = ((const float4*)pp)[c];
                s += (p.x + p.y) + (p.z + p.w);
            }
            rs[t] = 1.0f / s;
        }
        // rs is read only after the K-loop's final __syncthreads -> ordering safe
    }

    auto stage = [&](int buf, int k0) {   // 3 gl_lds16 per thread: A 256x32 (2), B 128x32 (1)
        gl_lds16(Abase + k0,        &As[buf][t * 8]);
        gl_lds16(Abase + k0 + r128, &As[buf][t * 8 + 4096]);
        gl_lds16(Bbase + k0,        &Bs[buf][t * 8]);
    };

    auto compute = [&](int buf) {
        bf16x8 af[4], bfr[4];
#pragma unroll
        for (int i = 0; i < 4; ++i)
            af[i] = *(const bf16x8*)(&As[buf][(wr * 64 + i * 16 + l16) * 32 + rdch]);
#pragma unroll
        for (int j = 0; j < 4; ++j)
            bfr[j] = *(const bf16x8*)(&Bs[buf][(wc * 64 + j * 16 + l16) * 32 + rdch]);
#pragma unroll
        for (int i = 0; i < 4; ++i)
#pragma unroll
            for (int j = 0; j < 4; ++j)
                acc[i][j] = __builtin_amdgcn_mfma_f32_16x16x32_bf16(af[i], bfr[j], acc[i][j], 0, 0, 0);
    };

    const int NT = K >> 5;
    stage(0, 0);
    __syncthreads();
    for (int it = 0; it < NT; ++it) {
        const int buf = it & 1;
        if (it + 1 < NT) stage(buf ^ 1, (it + 1) << 5);   // prefetch in flight during compute
        compute(buf);
        __syncthreads();
    }

    if (MODE == 1) {
        bf16* Cg = (bf16*)Cout + bz * batchC;
        const int slot = bn * 2 + wc;   // private slot per (n-block, wave-col): 16x2 = 32 slots
#pragma unroll
        for (int i = 0; i < 4; ++i)
#pragma unroll
            for (int r = 0; r < 4; ++r) {
                long long row = m0 + wr * 64 + i * 16 + quad * 4 + r;
                float s = 0.f;
#pragma unroll
                for (int j = 0; j < 4; ++j) {
                    float v = __expf(fast_tanh(acc[i][j][r]));
                    s += v;
                    Cg[row * (long long)N + (n0 + wc * 64 + j * 16 + l16)] = (bf16)v;
                }
#pragma unroll
                for (int msk = 1; msk < 16; msk <<= 1) s += __shfl_xor(s, msk);
                if (l16 == 0)
                    rpart[(bz * batchR + row) * NSLOT + slot] = s;   // plain store, race-free
            }
    } else if (MODE == 2) {
        float* Og = (float*)Cout + bz * batchC;
#pragma unroll
        for (int i = 0; i < 4; ++i)
#pragma unroll
            for (int r = 0; r < 4; ++r) {
                int rl = wr * 64 + i * 16 + quad * 4 + r;
                float inv = rs[rl];
                long long row = m0 + rl;
#pragma unroll
                for (int j = 0; j < 4; ++j)
                    Og[row * (long long)N + (n0 + wc * 64 + j * 16 + l16)] = acc[i][j][r] * inv;
            }
    } else {
        bf16* Cg = (bf16*)Cout + bz * batchC;
#pragma unroll
        for (int i = 0; i < 4; ++i)
#pragma unroll
            for (int r = 0; r < 4; ++r) {
                long long row = m0 + wr * 64 + i * 16 + quad * 4 + r;
#pragma unroll
                for (int j = 0; j < 4; ++j)
                    Cg[row * (long long)N + (n0 + wc * 64 + j * 16 + l16)] = (bf16)acc[i][j][r];
            }
    }
}

// ----------------------------------------------------------------
extern "C" void kernel_launch(void* const* d_in, const int* in_sizes, int n_in,
                              void* d_out, int out_size, void* d_ws, size_t ws_size,
                              hipStream_t stream) {
    const int B = 8, S = 2048, D = 512;
    const float* x = (const float*)d_in[0];
    const float* W = (const float*)d_in[1];
    float* out = (float*)d_out;

    const size_t nx = (size_t)B * S * D;
    const size_t nw = (size_t)D * D;

    char* ws = (char*)d_ws;
    auto al = [](size_t v) { return (v + 255) & ~(size_t)255; };
    size_t off = 0;
    bf16* xb = (bf16*)(ws + off); off = al(off + nx * 2);          // x bf16 [B,S,D]
    bf16* xt = (bf16*)(ws + off); off = al(off + nx * 2);          // x^T bf16 [B,D,S]
    bf16* pb = (bf16*)(ws + off); off = al(off + nx * 2);          // proj bf16 [B,S,D]
    bf16* wt = (bf16*)(ws + off); off = al(off + nw * 2);          // W^T bf16 [D,D]
    float* rpart = (float*)(ws + off); off = al(off + (size_t)B * S * NSLOT * 4);  // rowsum partials
    bf16* sb = (bf16*)(ws + off);                                  // P_unnorm bf16
    const size_t full_need = off + (size_t)B * S * S * 2;
    const bool batched = (ws_size >= full_need);

    { dim3 g(S / 64, D / 64, B); cast_both<<<g, 256, 0, stream>>>(x, xb, xt, S, D); }
    { dim3 g(D / 32, D / 32, 1); cast_transpose<<<g, 256, 0, stream>>>(W, wt, D, D); }

    // proj: pb[BS,D] = xb @ wt^T   (256x128 tiles, grid 64x4 = 256 blocks)
    {
        dim3 g(B * S / 256, D / 128, 1);
        gemm512<0><<<g, 512, 0, stream>>>(xb, wt, (void*)pb, nullptr, B * S, D, D, 0, 0, 0, 0);
    }

    const long long sd = (long long)S * D;
    const long long ss = (long long)S * S;

    if (batched) {
        // P_un = exp(tanh(pb @ xb^T)), rowsum partials   (grid 8x16x8 = 1024 blocks)
        dim3 g2(S / 256, S / 128, B);
        gemm512<1><<<g2, 512, 0, stream>>>(pb, xb, (void*)sb, rpart, S, S, D, sd, sd, ss, S);
        // out = (P_un @ xt^T) * invRowsum                (grid 8x4x8 = 256 blocks)
        dim3 g4(S / 256, D / 128, B);
        gemm512<2><<<g4, 512, 0, stream>>>(sb, xt, (void*)out, rpart, S, D, S, ss, sd, sd, S);
    } else {
        for (int b = 0; b < B; ++b) {
            dim3 g2(S / 256, S / 128, 1);
            gemm512<1><<<g2, 512, 0, stream>>>(pb + (size_t)b * sd, xb + (size_t)b * sd,
                                               (void*)sb, rpart + (size_t)b * S * NSLOT,
                                               S, S, D, 0, 0, 0, S);
            dim3 g4(S / 256, D / 128, 1);
            gemm512<2><<<g4, 512, 0, stream>>>(sb, xt + (size_t)b * sd,
                                               (void*)(out + (size_t)b * sd), rpart + (size_t)b * S * NSLOT,
                                               S, D, S, 0, 0, 0, S);
        }
    }
}

// Round 9
// 214.125 us; speedup vs baseline: 1.1273x; 1.0427x over previous
//
#include <hip/hip_runtime.h>
#include <hip/hip_bf16.h>

typedef __bf16 bf16;
typedef __attribute__((ext_vector_type(4))) __bf16 bf16x4;
typedef __attribute__((ext_vector_type(8))) __bf16 bf16x8;
typedef __attribute__((ext_vector_type(4))) float floatx4;

#define NSLOT 32   // rowsum partial slots per row: 16 n-blocks x 2 wave-cols (scores BN=128)

// async global->LDS, 16B per lane. LDS dest is wave-uniform base + lane*16 (HW-fixed);
// the GLOBAL source chunk is swizzled so LDS frag reads are conflict-free (R5/R12: conflicts 0).
__device__ __forceinline__ void gl_lds16(const bf16* g, bf16* l) {
    __builtin_amdgcn_global_load_lds(
        (const __attribute__((address_space(1))) unsigned int*)g,
        (__attribute__((address_space(3))) unsigned int*)l,
        16, 0, 0);
}

// 4(m) x 2(n) supertile swizzle: consecutive dispatch ids share A/B bands (L2 locality).
// Requires gridDim.x % 4 == 0 and gridDim.y % 2 == 0. Bijective on the grid.
__device__ __forceinline__ void swizzle_mn(int& bm, int& bn) {
    int gx = gridDim.x;
    int f  = blockIdx.y * gx + blockIdx.x;
    int st = f >> 3, r = f & 7;
    int mgroups = gx >> 2;
    bm = (st % mgroups) * 4 + (r & 3);
    bn = (st / mgroups) * 2 + (r >> 2);
}

// ---------------------------------------------------------------- x fp32 [R,C] -> xb bf16 [R,C] AND xt bf16 [C,R]
// R16: W-transpose merged in (z == B handles W -> wt; whole blocks branch, so __syncthreads
// stays block-uniform). Saves one kernel launch.
__global__ __launch_bounds__(256) void cast_both(const float* __restrict__ in,
                                                 bf16* __restrict__ outn,
                                                 bf16* __restrict__ outt,
                                                 int R, int C, int B,
                                                 const float* __restrict__ Wm,
                                                 bf16* __restrict__ wt) {
    __shared__ float tile[64][65];
    const int bz = blockIdx.z;
    const int cl = (threadIdx.x & 15) * 4;   // col offset within tile
    const int rw = threadIdx.x >> 4;         // 0..15

    if (bz == B) {                            // W path: 512x512 fp32 -> wt bf16 [D,D] transposed
        if (blockIdx.x >= 8 || blockIdx.y >= 8) return;   // block-uniform early exit
        const int r0 = blockIdx.x * 64, c0 = blockIdx.y * 64;
#pragma unroll
        for (int it = 0; it < 4; ++it) {
            const int r = rw + it * 16;
            floatx4 v = *(const floatx4*)&Wm[(long long)(r0 + r) * 512 + c0 + cl];
            tile[r][cl + 0] = v[0]; tile[r][cl + 1] = v[1];
            tile[r][cl + 2] = v[2]; tile[r][cl + 3] = v[3];
        }
        __syncthreads();
#pragma unroll
        for (int it = 0; it < 4; ++it) {
            const int c = rw + it * 16;
            bf16x4 b;
            b[0] = (bf16)tile[cl + 0][c]; b[1] = (bf16)tile[cl + 1][c];
            b[2] = (bf16)tile[cl + 2][c]; b[3] = (bf16)tile[cl + 3][c];
            *(bf16x4*)&wt[(long long)(c0 + c) * 512 + r0 + cl] = b;
        }
        return;
    }

    in   += (long long)bz * R * C;
    outn += (long long)bz * R * C;
    outt += (long long)bz * R * C;
    const int r0 = blockIdx.x * 64, c0 = blockIdx.y * 64;
#pragma unroll
    for (int it = 0; it < 4; ++it) {
        const int r = rw + it * 16;
        floatx4 v = *(const floatx4*)&in[(long long)(r0 + r) * C + c0 + cl];
        bf16x4 b; b[0] = (bf16)v[0]; b[1] = (bf16)v[1]; b[2] = (bf16)v[2]; b[3] = (bf16)v[3];
        *(bf16x4*)&outn[(long long)(r0 + r) * C + c0 + cl] = b;
        tile[r][cl + 0] = v[0]; tile[r][cl + 1] = v[1];
        tile[r][cl + 2] = v[2]; tile[r][cl + 3] = v[3];
    }
    __syncthreads();
#pragma unroll
    for (int it = 0; it < 4; ++it) {
        const int c = rw + it * 16;          // original col = outt row
        bf16x4 b;
        b[0] = (bf16)tile[cl + 0][c]; b[1] = (bf16)tile[cl + 1][c];
        b[2] = (bf16)tile[cl + 2][c]; b[3] = (bf16)tile[cl + 3][c];
        *(bf16x4*)&outt[(long long)(c0 + c) * R + r0 + cl] = b;
    }
}

// tanh via one exp + one rcp; exact saturation at +-1. (R7: poly outer-exp regressed; keep __expf.)
__device__ __forceinline__ float fast_tanh(float v) {
    float e = __expf(2.0f * v);
    return 1.0f - 2.0f / (e + 1.0f);
}

// ---------------------------------------------------------------- 256(M)xBN(N) tile, 512 thr, BK=32
// R15 result: 512-thr blocks raised waves/CU (occupancy 26.5->35%) and cut scores 71.6->64.6 us —
// the only lever that has moved time in 6 rounds. R16: extend to the two 1-block/CU kernels.
//   BN=128 (scores): 8 waves 4Mx2N, 64x64 wave tiles, grid 1024 (unchanged control).
//   BN=64 (PV/proj): 8 waves 8Mx1N, 32x64 wave tiles, grid 512 = 2 blocks/CU = 16 waves/CU
//                    (was 256 = 1 block/CU = 8 waves, the slow regime). LDS 40 KB, acc 32 VGPR.
// Same proven BK=32 2-phase dbuf loop + staging/read swizzles (SQ_LDS_BANK_CONFLICT = 0).
// MODE 0 (proj): bf16 C.  MODE 1 (scores): bf16 exp(tanh(v)) + rowsum partials.  MODE 2 (PV): fp32 v*invRowsum.
template <int MODE, int BN>
__global__ __launch_bounds__(512, 4) void gemm512(const bf16* __restrict__ A,
                                                  const bf16* __restrict__ Bm,
                                                  void* __restrict__ Cout,
                                                  float* __restrict__ rpart,
                                                  int M, int N, int K,
                                                  long long batchA, long long batchB,
                                                  long long batchC, long long batchR) {
    constexpr int NI = (BN == 128) ? 4 : 2;   // A-side 16-row frags per wave (wave rows = NI*16)

    const long long bz = blockIdx.z;
    A  += bz * batchA;
    Bm += bz * batchB;

    __shared__ bf16 As[2][256 * 32];   // 2 x 16 KB
    __shared__ bf16 Bs[2][BN * 32];    // 2 x 8 or 4 KB
    __shared__ float rs[256];          // MODE 2 only

    const int t    = threadIdx.x;      // 0..511
    const int lane = t & 63;
    const int w    = t >> 6;           // 0..7
    const int quad = lane >> 4;
    const int l16  = lane & 15;
    const int wr   = (BN == 128) ? (w >> 1) : w;   // M block index (64 or 32 rows)
    const int wc   = (BN == 128) ? (w & 1) : 0;    // N block index

    int bm, bn;
    swizzle_mn(bm, bn);
    const int m0 = bm * 256;
    const int n0 = bn * BN;

    floatx4 acc[NI][4] = {};

    // staging: thread t covers row srow (A: +128 on 2nd instr), global chunk (t&3)^((t>>3)&3).
    const int srow = t >> 2;                         // 0..127
    const int sch  = (((t & 3) ^ ((t >> 3) & 3))) * 8;
    const bf16* Abase = A + (long long)(m0 + srow) * K + sch;
    const bf16* Bbase = Bm + (long long)(n0 + srow) * K + sch;
    const long long r128 = 128LL * K;

    // frag reads: logical chunk quad after inverse swizzle (2-way max aliasing = free, m136)
    const int rdch = (quad ^ ((l16 >> 1) & 3)) * 8;

    // MODE 2: fold softmax denominators (sum of NSLOT partials per row) into rs[] up front.
    if (MODE == 2) {
        if (t < 256) {
            const float* pp = rpart + (bz * batchR + m0 + t) * NSLOT;
            float s = 0.f;
#pragma unroll
            for (int c = 0; c < NSLOT / 4; ++c) {
                float4 p = ((const float4*)pp)[c];
                s += (p.x + p.y) + (p.z + p.w);
            }
            rs[t] = 1.0f / s;
        }
        // rs is read only after the K-loop's final __syncthreads -> ordering safe
    }

    auto stage = [&](int buf, int k0) {
        gl_lds16(Abase + k0,        &As[buf][t * 8]);
        gl_lds16(Abase + k0 + r128, &As[buf][t * 8 + 4096]);
        if (BN == 128) {
            gl_lds16(Bbase + k0, &Bs[buf][t * 8]);          // 128x32: all 512 threads
        } else {
            if (t < 256) gl_lds16(Bbase + k0, &Bs[buf][t * 8]);   // 64x32: waves 0-3 (wave-uniform)
        }
    };

    auto compute = [&](int buf) {
        bf16x8 af[NI], bfr[4];
#pragma unroll
        for (int i = 0; i < NI; ++i)
            af[i] = *(const bf16x8*)(&As[buf][(wr * (NI * 16) + i * 16 + l16) * 32 + rdch]);
#pragma unroll
        for (int j = 0; j < 4; ++j)
            bfr[j] = *(const bf16x8*)(&Bs[buf][(wc * 64 + j * 16 + l16) * 32 + rdch]);
#pragma unroll
        for (int i = 0; i < NI; ++i)
#pragma unroll
            for (int j = 0; j < 4; ++j)
                acc[i][j] = __builtin_amdgcn_mfma_f32_16x16x32_bf16(af[i], bfr[j], acc[i][j], 0, 0, 0);
    };

    const int NT = K >> 5;
    stage(0, 0);
    __syncthreads();
    for (int it = 0; it < NT; ++it) {
        const int buf = it & 1;
        if (it + 1 < NT) stage(buf ^ 1, (it + 1) << 5);   // prefetch in flight during compute
        compute(buf);
        __syncthreads();
    }

    if (MODE == 1) {
        bf16* Cg = (bf16*)Cout + bz * batchC;
        const int slot = bn * 2 + wc;   // private slot per (n-block, wave-col): 16x2 = 32 slots
#pragma unroll
        for (int i = 0; i < NI; ++i)
#pragma unroll
            for (int r = 0; r < 4; ++r) {
                long long row = m0 + wr * (NI * 16) + i * 16 + quad * 4 + r;
                float s = 0.f;
#pragma unroll
                for (int j = 0; j < 4; ++j) {
                    float v = __expf(fast_tanh(acc[i][j][r]));
                    s += v;
                    Cg[row * (long long)N + (n0 + wc * 64 + j * 16 + l16)] = (bf16)v;
                }
#pragma unroll
                for (int msk = 1; msk < 16; msk <<= 1) s += __shfl_xor(s, msk);
                if (l16 == 0)
                    rpart[(bz * batchR + row) * NSLOT + slot] = s;   // plain store, race-free
            }
    } else if (MODE == 2) {
        float* Og = (float*)Cout + bz * batchC;
#pragma unroll
        for (int i = 0; i < NI; ++i)
#pragma unroll
            for (int r = 0; r < 4; ++r) {
                int rl = wr * (NI * 16) + i * 16 + quad * 4 + r;
                float inv = rs[rl];
                long long row = m0 + rl;
#pragma unroll
                for (int j = 0; j < 4; ++j)
                    Og[row * (long long)N + (n0 + wc * 64 + j * 16 + l16)] = acc[i][j][r] * inv;
            }
    } else {
        bf16* Cg = (bf16*)Cout + bz * batchC;
#pragma unroll
        for (int i = 0; i < NI; ++i)
#pragma unroll
            for (int r = 0; r < 4; ++r) {
                long long row = m0 + wr * (NI * 16) + i * 16 + quad * 4 + r;
#pragma unroll
                for (int j = 0; j < 4; ++j)
                    Cg[row * (long long)N + (n0 + wc * 64 + j * 16 + l16)] = (bf16)acc[i][j][r];
            }
    }
}

// ----------------------------------------------------------------
extern "C" void kernel_launch(void* const* d_in, const int* in_sizes, int n_in,
                              void* d_out, int out_size, void* d_ws, size_t ws_size,
                              hipStream_t stream) {
    const int B = 8, S = 2048, D = 512;
    const float* x = (const float*)d_in[0];
    const float* W = (const float*)d_in[1];
    float* out = (float*)d_out;

    const size_t nx = (size_t)B * S * D;
    const size_t nw = (size_t)D * D;

    char* ws = (char*)d_ws;
    auto al = [](size_t v) { return (v + 255) & ~(size_t)255; };
    size_t off = 0;
    bf16* xb = (bf16*)(ws + off); off = al(off + nx * 2);          // x bf16 [B,S,D]
    bf16* xt = (bf16*)(ws + off); off = al(off + nx * 2);          // x^T bf16 [B,D,S]
    bf16* pb = (bf16*)(ws + off); off = al(off + nx * 2);          // proj bf16 [B,S,D]
    bf16* wt = (bf16*)(ws + off); off = al(off + nw * 2);          // W^T bf16 [D,D]
    float* rpart = (float*)(ws + off); off = al(off + (size_t)B * S * NSLOT * 4);  // rowsum partials
    bf16* sb = (bf16*)(ws + off);                                  // P_unnorm bf16
    const size_t full_need = off + (size_t)B * S * S * 2;
    const bool batched = (ws_size >= full_need);

    // casts: x -> xb,xt (z = 0..B-1) and W -> wt (z = B)
    { dim3 g(S / 64, D / 64, B + 1); cast_both<<<g, 256, 0, stream>>>(x, xb, xt, S, D, B, W, wt); }

    // proj: pb[BS,D] = xb @ wt^T   (256x64 tiles, grid 64x8 = 512 blocks = 2/CU)
    {
        dim3 g(B * S / 256, D / 64, 1);
        gemm512<0, 64><<<g, 512, 0, stream>>>(xb, wt, (void*)pb, nullptr, B * S, D, D, 0, 0, 0, 0);
    }

    const long long sd = (long long)S * D;
    const long long ss = (long long)S * S;

    if (batched) {
        // P_un = exp(tanh(pb @ xb^T)), rowsum partials   (256x128 tiles, grid 8x16x8 = 1024)
        dim3 g2(S / 256, S / 128, B);
        gemm512<1, 128><<<g2, 512, 0, stream>>>(pb, xb, (void*)sb, rpart, S, S, D, sd, sd, ss, S);
        // out = (P_un @ xt^T) * invRowsum                (256x64 tiles, grid 8x8x8 = 512 = 2/CU)
        dim3 g4(S / 256, D / 64, B);
        gemm512<2, 64><<<g4, 512, 0, stream>>>(sb, xt, (void*)out, rpart, S, D, S, ss, sd, sd, S);
    } else {
        for (int b = 0; b < B; ++b) {
            dim3 g2(S / 256, S / 128, 1);
            gemm512<1, 128><<<g2, 512, 0, stream>>>(pb + (size_t)b * sd, xb + (size_t)b * sd,
                                                    (void*)sb, rpart + (size_t)b * S * NSLOT,
                                                    S, S, D, 0, 0, 0, S);
            dim3 g4(S / 256, D / 64, 1);
            gemm512<2, 64><<<g4, 512, 0, stream>>>(sb, xt + (size_t)b * sd,
                                                   (void*)(out + (size_t)b * sd), rpart + (size_t)b * S * NSLOT,
                                                   S, D, S, 0, 0, 0, S);
        }
    }
}